// Round 1
// baseline (719.131 us; speedup 1.0000x reference)
//
#include <hip/hip_runtime.h>
#include <math.h>

#define IGNORE_INDEX (-100)

// ---------------- Kernel 1: per-row online-softmax NLL ----------------
// One block (256 threads = 4 waves) per row of [B*S, V] logits.
// Single pass over global memory: online (max, scaled-sum) per thread,
// wave shfl reduction, cross-wave LDS combine, then one atomicAdd per row.
__global__ __launch_bounds__(256) void nll_rows_kernel(
    const float* __restrict__ logits,
    const int*   __restrict__ labels,
    float* __restrict__ ws_sum,   // accumulated sum of nll over valid rows
    int*   __restrict__ ws_cnt,   // count of valid rows
    int V)
{
    const int row   = blockIdx.x;
    const int label = labels[row];
    if (label == IGNORE_INDEX) return;   // contributes neither nll nor count

    const float* __restrict__ rowp = logits + (size_t)row * (size_t)V;
    const int tid = threadIdx.x;

    // Online softmax accumulation, float4-vectorized (V=32000 -> 8000 float4).
    float m = -INFINITY;
    float s = 0.0f;
    const float4* __restrict__ r4 = reinterpret_cast<const float4*>(rowp);
    const int n4 = V >> 2;
    for (int i = tid; i < n4; i += 256) {
        float4 v = r4[i];
        float x;
        x = v.x; { float nm = fmaxf(m, x); s = s * __expf(m - nm) + __expf(x - nm); m = nm; }
        x = v.y; { float nm = fmaxf(m, x); s = s * __expf(m - nm) + __expf(x - nm); m = nm; }
        x = v.z; { float nm = fmaxf(m, x); s = s * __expf(m - nm) + __expf(x - nm); m = nm; }
        x = v.w; { float nm = fmaxf(m, x); s = s * __expf(m - nm) + __expf(x - nm); m = nm; }
    }
    // Handle V not divisible by 4 (not hit for V=32000, kept for generality).
    for (int i = (n4 << 2) + tid; i < V; i += 256) {
        float x = rowp[i];
        float nm = fmaxf(m, x); s = s * __expf(m - nm) + __expf(x - nm); m = nm;
    }

    // Wave (64-lane) butterfly reduction of (m, s).
    #pragma unroll
    for (int off = 32; off > 0; off >>= 1) {
        float om = __shfl_xor(m, off, 64);
        float os = __shfl_xor(s, off, 64);
        float nm = fmaxf(m, om);
        s = s * __expf(m - nm) + os * __expf(om - nm);
        m = nm;
    }

    // Cross-wave combine (4 waves) via LDS.
    __shared__ float sm[4];
    __shared__ float ss[4];
    if ((tid & 63) == 0) { sm[tid >> 6] = m; ss[tid >> 6] = s; }
    __syncthreads();
    if (tid == 0) {
        m = sm[0]; s = ss[0];
        #pragma unroll
        for (int w = 1; w < 4; ++w) {
            float om = sm[w], os = ss[w];
            float nm = fmaxf(m, om);
            s = s * __expf(m - nm) + os * __expf(om - nm);
            m = nm;
        }
        // logsumexp = m + log(s);  nll = -(x_label - logsumexp)
        float xl  = rowp[label];
        float nll = -(xl - m - logf(s));
        atomicAdd(ws_sum, nll);
        atomicAdd(ws_cnt, 1);
    }
}

// ---------------- Kernel 2: RankNet pairwise loss + finalize ----------------
// Single block. N is small (64). Runs after kernel 1 (same stream).
__global__ __launch_bounds__(256) void rank_finalize_kernel(
    const float* __restrict__ rlogits,
    const int*   __restrict__ rankings,
    const float* __restrict__ ws_sum,
    const int*   __restrict__ ws_cnt,
    float* __restrict__ out,
    int N)
{
    __shared__ float sl[256];
    __shared__ float sr[256];
    const int tid = threadIdx.x;
    if (tid < N) { sl[tid] = rlogits[tid]; sr[tid] = (float)rankings[tid]; }
    __syncthreads();

    float acc = 0.0f;
    const int NP = N * N;
    for (int p = tid; p < NP; p += 256) {
        const int i = p / N;
        const int j = p - i * N;
        if (i < j) {
            const float ri = sr[i], rj = sr[j];
            if (ri < rj) {
                // softplus(logits[j] - logits[i]), numerically stable
                const float d  = sl[j] - sl[i];
                const float sp = fmaxf(d, 0.0f) + log1pf(expf(-fabsf(d)));
                acc += sp / (ri + rj);
            }
        }
    }

    // Block reduction of acc.
    #pragma unroll
    for (int off = 32; off > 0; off >>= 1) acc += __shfl_xor(acc, off, 64);
    __shared__ float part[4];
    if ((tid & 63) == 0) part[tid >> 6] = acc;
    __syncthreads();
    if (tid == 0) {
        const float rank_sum  = part[0] + part[1] + part[2] + part[3];
        const float rank_loss = rank_sum / (float)N;
        const float nv        = fmaxf((float)(*ws_cnt), 1.0f);
        const float lm_loss   = (*ws_sum) / nv;
        out[0] = lm_loss + 10.0f * rank_loss;
    }
}

extern "C" void kernel_launch(void* const* d_in, const int* in_sizes, int n_in,
                              void* d_out, int out_size, void* d_ws, size_t ws_size,
                              hipStream_t stream) {
    const float* lm_logits = (const float*)d_in[0];
    const int*   lm_labels = (const int*)d_in[1];
    const float* rlogits   = (const float*)d_in[2];
    const int*   rankings  = (const int*)d_in[3];

    const int BS = in_sizes[1];               // B*S = 4096 rows
    const int V  = in_sizes[0] / BS;          // 32000
    const int N  = in_sizes[2];               // 64

    float* ws_sum = (float*)d_ws;
    int*   ws_cnt = (int*)d_ws + 1;

    // d_ws is poisoned to 0xAA before every timed launch: zero the accumulators.
    hipMemsetAsync(d_ws, 0, 2 * sizeof(float), stream);

    nll_rows_kernel<<<BS, 256, 0, stream>>>(lm_logits, lm_labels, ws_sum, ws_cnt, V);
    rank_finalize_kernel<<<1, 256, 0, stream>>>(rlogits, rankings, ws_sum, ws_cnt,
                                                (float*)d_out, N);
}